// Round 1
// baseline (289.070 us; speedup 1.0000x reference)
//
#include <hip/hip_runtime.h>
#include <math.h>

#define S_LEN 512
#define BATCH 16
#define DIN   512
#define DF    512
#define NMIX  10
#define NCHAR 1024
#define DCTX  256
#define M_ROWS (S_LEN*BATCH)   // 8192

// d_out layout (tuple flattened in return order)
#define OFF_CTXOUT 0
#define OFF_ATTN   (S_LEN*BATCH*DCTX)                    // 2,097,152
#define OFF_MEANS  (OFF_ATTN + S_LEN*BATCH*NCHAR)        // +8,388,608
#define OFF_VARS   (OFF_MEANS + S_LEN*BATCH*NMIX)
#define OFF_WTS    (OFF_VARS  + S_LEN*BATCH*NMIX)

// ---------------------------------------------------------------------------
// Kernel 1: fused MLP.  16 rows/block.  h tile lives entirely in LDS.
//   h = leaky_relu(X@W1 + b1); outs = softplus(h@W2 + b2)
//   delta/25 -> means region (raw deltas, cumsum'd by kernel 2)
//   clip(vars) -> vars region; weights -> wts region
// ---------------------------------------------------------------------------
__global__ __launch_bounds__(256) void mlp_kernel(
    const float* __restrict__ X,  const float* __restrict__ W1,
    const float* __restrict__ b1, const float* __restrict__ W2,
    const float* __restrict__ b2,
    float* __restrict__ dmeans, float* __restrict__ dvars, float* __restrict__ dwts)
{
    __shared__ float xs[16*512];   // 32 KB
    __shared__ float hs[16*512];   // 32 KB
    const int tid  = threadIdx.x;
    const int row0 = blockIdx.x * 16;

    // Load 16 input rows (8192 contiguous floats) coalesced as float4
    {
        const float4* src = (const float4*)(X + (size_t)row0 * DIN);
        float4* dst = (float4*)xs;
        #pragma unroll
        for (int i = 0; i < 8; i++) dst[tid + i*256] = src[tid + i*256];
    }
    __syncthreads();

    // Phase B: h = leaky_relu(xs @ W1 + b1). Thread owns 2 adjacent cols.
    const int n0 = tid * 2;
    float acc0[16], acc1[16];
    #pragma unroll
    for (int r = 0; r < 16; r++) { acc0[r] = 0.f; acc1[r] = 0.f; }

    for (int k0 = 0; k0 < DIN; k0 += 4) {
        float2 w0 = *(const float2*)(W1 + (size_t)(k0+0)*DF + n0);
        float2 w1 = *(const float2*)(W1 + (size_t)(k0+1)*DF + n0);
        float2 w2 = *(const float2*)(W1 + (size_t)(k0+2)*DF + n0);
        float2 w3 = *(const float2*)(W1 + (size_t)(k0+3)*DF + n0);
        #pragma unroll
        for (int r = 0; r < 16; r++) {
            float4 x = *(const float4*)(xs + r*512 + k0);   // LDS broadcast
            acc0[r] = fmaf(x.x, w0.x, acc0[r]);
            acc1[r] = fmaf(x.x, w0.y, acc1[r]);
            acc0[r] = fmaf(x.y, w1.x, acc0[r]);
            acc1[r] = fmaf(x.y, w1.y, acc1[r]);
            acc0[r] = fmaf(x.z, w2.x, acc0[r]);
            acc1[r] = fmaf(x.z, w2.y, acc1[r]);
            acc0[r] = fmaf(x.w, w3.x, acc0[r]);
            acc1[r] = fmaf(x.w, w3.y, acc1[r]);
        }
    }
    {
        float2 bb = *(const float2*)(b1 + n0);
        #pragma unroll
        for (int r = 0; r < 16; r++) {
            float h0 = acc0[r] + bb.x;
            float h1 = acc1[r] + bb.y;
            h0 = h0 > 0.f ? h0 : 0.01f * h0;
            h1 = h1 > 0.f ? h1 : 0.01f * h1;
            *(float2*)(hs + r*512 + n0) = make_float2(h0, h1);
        }
    }
    __syncthreads();

    // Phase C: outs = softplus(hs @ W2 + b2), split into the three heads
    for (int idx = tid; idx < 16*30; idx += 256) {
        const int r = idx / 30;
        const int j = idx % 30;
        float dot = 0.f;
        for (int k0 = 0; k0 < DF; k0 += 4) {
            float4 h4 = *(const float4*)(hs + r*512 + k0);
            dot = fmaf(h4.x, W2[(k0+0)*30 + j], dot);
            dot = fmaf(h4.y, W2[(k0+1)*30 + j], dot);
            dot = fmaf(h4.z, W2[(k0+2)*30 + j], dot);
            dot = fmaf(h4.w, W2[(k0+3)*30 + j], dot);
        }
        dot += b2[j];
        // stable softplus
        float sp = fmaxf(dot, 0.f) + log1pf(__expf(-fabsf(dot)));
        const int row = row0 + r;
        if (j < 10)       dmeans[row*NMIX + j]        = sp / 25.0f;
        else if (j < 20)  dvars [row*NMIX + (j-10)]   = fminf(fmaxf(sp, 0.01f), 100.f);
        else              dwts  [row*NMIX + (j-20)]   = sp;
    }
}

// ---------------------------------------------------------------------------
// Kernel 2: cumsum over S, in-place on the means region (holds raw deltas).
// 160 independent (b,k) scans; consecutive threads hit consecutive addresses.
// ---------------------------------------------------------------------------
__global__ __launch_bounds__(256) void cumsum_kernel(
    const float* __restrict__ init_means, float* __restrict__ means)
{
    const int tid = threadIdx.x;
    if (tid >= BATCH*NMIX) return;      // 160 active lanes
    float acc = init_means[tid];        // init_means (B,K) flat == pair index
    #pragma unroll 4
    for (int s = 0; s < S_LEN; s++) {
        float v = means[s*(BATCH*NMIX) + tid];
        acc += v;
        means[s*(BATCH*NMIX) + tid] = acc;
    }
}

// ---------------------------------------------------------------------------
// Kernel 3: attention weights.  One block per (s,b) row; 4 t's per thread.
//   attn[t] = sum_k w_k * exp(-(t - m_k)^2 * v_k)     (== exp(logsumexp))
// ---------------------------------------------------------------------------
__global__ __launch_bounds__(256) void attn_kernel(
    const float* __restrict__ means, const float* __restrict__ vars,
    const float* __restrict__ wts,   float* __restrict__ attn)
{
    const int row = blockIdx.x;          // s*B + b
    const int tid = threadIdx.x;
    float m[NMIX], v[NMIX], w[NMIX];
    #pragma unroll
    for (int k = 0; k < NMIX; k++) {
        m[k] = means[row*NMIX + k];
        v[k] = vars [row*NMIX + k];
        w[k] = wts  [row*NMIX + k];
    }
    const int t0 = tid * 4;
    float o[4];
    #pragma unroll
    for (int i = 0; i < 4; i++) {
        const float t = (float)(t0 + i);
        float sum = 0.f;
        #pragma unroll
        for (int k = 0; k < NMIX; k++) {
            float d = t - m[k];
            sum += w[k] * __expf(-d*d*v[k]);
        }
        o[i] = sum;
    }
    *(float4*)(attn + (size_t)row*NCHAR + t0) = make_float4(o[0],o[1],o[2],o[3]);
}

// ---------------------------------------------------------------------------
// Kernel 4: attended contexts.  Per-batch GEMM (512x1024)@(1024x256).
// 64x64 tile, BK=16, 256 threads, 4x4 microtile per thread.
// ---------------------------------------------------------------------------
__global__ __launch_bounds__(256) void ctx_kernel(
    const float* __restrict__ attn, const float* __restrict__ ctx,
    float* __restrict__ out)
{
    __shared__ float As[16*68];   // [k][s_local], padded stride 68
    __shared__ float Bs[16*68];   // [k][d_local]
    const int bid = blockIdx.x;
    const int b   = bid >> 5;         // /32
    const int rem = bid & 31;
    const int s0  = (rem >> 2) * 64;
    const int d0  = (rem & 3)  * 64;
    const int tid = threadIdx.x;
    const int tx  = tid & 15;
    const int ty  = tid >> 4;

    const int arow = tid >> 2;            // 0..63
    const int atq  = (tid & 3) * 4;       // 0,4,8,12
    const int bt   = tid >> 4;            // 0..15
    const int bd   = (tid & 15) * 4;

    const float* aptr = attn + (size_t)(s0 + arow)*(BATCH*NCHAR) + b*NCHAR + atq;
    const float* bptr = ctx  + (size_t)bt*(BATCH*DCTX) + b*DCTX + d0 + bd;

    float c[4][4];
    #pragma unroll
    for (int i = 0; i < 4; i++)
        #pragma unroll
        for (int j = 0; j < 4; j++) c[i][j] = 0.f;

    for (int kt = 0; kt < NCHAR; kt += 16) {
        float4 a  = *(const float4*)(aptr + kt);
        float4 bv = *(const float4*)(bptr + (size_t)kt*(BATCH*DCTX));
        __syncthreads();
        As[(atq+0)*68 + arow] = a.x;
        As[(atq+1)*68 + arow] = a.y;
        As[(atq+2)*68 + arow] = a.z;
        As[(atq+3)*68 + arow] = a.w;
        *(float4*)(Bs + bt*68 + bd) = bv;
        __syncthreads();
        #pragma unroll
        for (int k = 0; k < 16; k++) {
            float4 a4 = *(const float4*)(As + k*68 + ty*4);
            float4 b4 = *(const float4*)(Bs + k*68 + tx*4);
            c[0][0] = fmaf(a4.x, b4.x, c[0][0]);
            c[0][1] = fmaf(a4.x, b4.y, c[0][1]);
            c[0][2] = fmaf(a4.x, b4.z, c[0][2]);
            c[0][3] = fmaf(a4.x, b4.w, c[0][3]);
            c[1][0] = fmaf(a4.y, b4.x, c[1][0]);
            c[1][1] = fmaf(a4.y, b4.y, c[1][1]);
            c[1][2] = fmaf(a4.y, b4.z, c[1][2]);
            c[1][3] = fmaf(a4.y, b4.w, c[1][3]);
            c[2][0] = fmaf(a4.z, b4.x, c[2][0]);
            c[2][1] = fmaf(a4.z, b4.y, c[2][1]);
            c[2][2] = fmaf(a4.z, b4.z, c[2][2]);
            c[2][3] = fmaf(a4.z, b4.w, c[2][3]);
            c[3][0] = fmaf(a4.w, b4.x, c[3][0]);
            c[3][1] = fmaf(a4.w, b4.y, c[3][1]);
            c[3][2] = fmaf(a4.w, b4.z, c[3][2]);
            c[3][3] = fmaf(a4.w, b4.w, c[3][3]);
        }
    }
    #pragma unroll
    for (int i = 0; i < 4; i++) {
        const int s = s0 + ty*4 + i;
        *(float4*)(out + (size_t)s*(BATCH*DCTX) + b*DCTX + d0 + tx*4)
            = make_float4(c[i][0], c[i][1], c[i][2], c[i][3]);
    }
}

// ---------------------------------------------------------------------------
extern "C" void kernel_launch(void* const* d_in, const int* in_sizes, int n_in,
                              void* d_out, int out_size, void* d_ws, size_t ws_size,
                              hipStream_t stream)
{
    const float* X     = (const float*)d_in[0];   // (S,B,512)
    const float* ctx   = (const float*)d_in[1];   // (1024,B,256)
    const float* initm = (const float*)d_in[2];   // (B,10)
    const float* W1    = (const float*)d_in[3];   // (512,512)
    const float* b1    = (const float*)d_in[4];   // (512,)
    const float* W2    = (const float*)d_in[5];   // (512,30)
    const float* b2    = (const float*)d_in[6];   // (30,)
    // d_in[7] = extra_chars (scalar 0, unused)

    float* out      = (float*)d_out;
    float* out_ctx  = out + OFF_CTXOUT;
    float* out_attn = out + OFF_ATTN;
    float* out_mean = out + OFF_MEANS;
    float* out_var  = out + OFF_VARS;
    float* out_wts  = out + OFF_WTS;

    mlp_kernel<<<M_ROWS/16, 256, 0, stream>>>(X, W1, b1, W2, b2,
                                              out_mean, out_var, out_wts);
    cumsum_kernel<<<1, 256, 0, stream>>>(initm, out_mean);
    attn_kernel<<<M_ROWS, 256, 0, stream>>>(out_mean, out_var, out_wts, out_attn);
    ctx_kernel<<<(NCHAR/NCHAR)*16*32, 256, 0, stream>>>(out_attn, ctx, out_ctx);
}

// Round 2
// 229.540 us; speedup vs baseline: 1.2593x; 1.2593x over previous
//
#include <hip/hip_runtime.h>
#include <math.h>

#define S_LEN 512
#define BATCH 16
#define DIN   512
#define DF    512
#define NMIX  10
#define NCHAR 1024
#define DCTX  256
#define M_ROWS (S_LEN*BATCH)   // 8192

// d_out layout (tuple flattened in return order)
#define OFF_CTXOUT 0
#define OFF_ATTN   (S_LEN*BATCH*DCTX)
#define OFF_MEANS  (OFF_ATTN + S_LEN*BATCH*NCHAR)
#define OFF_VARS   (OFF_MEANS + S_LEN*BATCH*NMIX)
#define OFF_WTS    (OFF_VARS  + S_LEN*BATCH*NMIX)

typedef short s16x8  __attribute__((ext_vector_type(8)));
typedef float f32x16 __attribute__((ext_vector_type(16)));

__device__ __forceinline__ unsigned short f2bf(float x) {
    unsigned int u = __float_as_uint(x);
    u += 0x7fffu + ((u >> 16) & 1u);     // round-to-nearest-even
    return (unsigned short)(u >> 16);
}

// ---------------------------------------------------------------------------
// Kernel 1: fused MLP.  16 rows/block.  Single 32KB LDS buffer reused
// (xs for GEMM1 input, then overwritten with h for GEMM2) -> 5 blocks/CU.
// ---------------------------------------------------------------------------
__global__ __launch_bounds__(256) void mlp_kernel(
    const float* __restrict__ X,  const float* __restrict__ W1,
    const float* __restrict__ b1, const float* __restrict__ W2,
    const float* __restrict__ b2,
    float* __restrict__ dmeans, float* __restrict__ dvars, float* __restrict__ dwts)
{
    __shared__ float xs[16*512];   // 32 KB, reused as h after Phase B
    const int tid  = threadIdx.x;
    const int row0 = blockIdx.x * 16;

    {   // load 16 input rows coalesced
        const float4* src = (const float4*)(X + (size_t)row0 * DIN);
        float4* dst = (float4*)xs;
        #pragma unroll
        for (int i = 0; i < 8; i++) dst[tid + i*256] = src[tid + i*256];
    }
    __syncthreads();

    // Phase B: h = leaky_relu(xs @ W1 + b1). Thread owns 2 adjacent cols.
    const int n0 = tid * 2;
    float acc0[16], acc1[16];
    #pragma unroll
    for (int r = 0; r < 16; r++) { acc0[r] = 0.f; acc1[r] = 0.f; }

    for (int k0 = 0; k0 < DIN; k0 += 4) {
        float2 w0 = *(const float2*)(W1 + (size_t)(k0+0)*DF + n0);
        float2 w1 = *(const float2*)(W1 + (size_t)(k0+1)*DF + n0);
        float2 w2 = *(const float2*)(W1 + (size_t)(k0+2)*DF + n0);
        float2 w3 = *(const float2*)(W1 + (size_t)(k0+3)*DF + n0);
        #pragma unroll
        for (int r = 0; r < 16; r++) {
            float4 x = *(const float4*)(xs + r*512 + k0);   // LDS broadcast
            acc0[r] = fmaf(x.x, w0.x, acc0[r]);
            acc1[r] = fmaf(x.x, w0.y, acc1[r]);
            acc0[r] = fmaf(x.y, w1.x, acc0[r]);
            acc1[r] = fmaf(x.y, w1.y, acc1[r]);
            acc0[r] = fmaf(x.z, w2.x, acc0[r]);
            acc1[r] = fmaf(x.z, w2.y, acc1[r]);
            acc0[r] = fmaf(x.w, w3.x, acc0[r]);
            acc1[r] = fmaf(x.w, w3.y, acc1[r]);
        }
    }
    __syncthreads();   // everyone done READING xs before we overwrite it
    {
        float2 bb = *(const float2*)(b1 + n0);
        #pragma unroll
        for (int r = 0; r < 16; r++) {
            float h0 = acc0[r] + bb.x;
            float h1 = acc1[r] + bb.y;
            h0 = h0 > 0.f ? h0 : 0.01f * h0;
            h1 = h1 > 0.f ? h1 : 0.01f * h1;
            *(float2*)(xs + r*512 + n0) = make_float2(h0, h1);
        }
    }
    __syncthreads();

    // Phase C: outs = softplus(h @ W2 + b2), 4 accumulator chains
    for (int idx = tid; idx < 16*30; idx += 256) {
        const int r = idx / 30;
        const int j = idx % 30;
        float d0 = 0.f, d1 = 0.f, d2 = 0.f, d3 = 0.f;
        for (int k0 = 0; k0 < DF; k0 += 16) {
            float4 h0 = *(const float4*)(xs + r*512 + k0);
            float4 h1 = *(const float4*)(xs + r*512 + k0 + 4);
            float4 h2 = *(const float4*)(xs + r*512 + k0 + 8);
            float4 h3 = *(const float4*)(xs + r*512 + k0 + 12);
            d0 = fmaf(h0.x, W2[(k0+ 0)*30 + j], d0);
            d0 = fmaf(h0.y, W2[(k0+ 1)*30 + j], d0);
            d0 = fmaf(h0.z, W2[(k0+ 2)*30 + j], d0);
            d0 = fmaf(h0.w, W2[(k0+ 3)*30 + j], d0);
            d1 = fmaf(h1.x, W2[(k0+ 4)*30 + j], d1);
            d1 = fmaf(h1.y, W2[(k0+ 5)*30 + j], d1);
            d1 = fmaf(h1.z, W2[(k0+ 6)*30 + j], d1);
            d1 = fmaf(h1.w, W2[(k0+ 7)*30 + j], d1);
            d2 = fmaf(h2.x, W2[(k0+ 8)*30 + j], d2);
            d2 = fmaf(h2.y, W2[(k0+ 9)*30 + j], d2);
            d2 = fmaf(h2.z, W2[(k0+10)*30 + j], d2);
            d2 = fmaf(h2.w, W2[(k0+11)*30 + j], d2);
            d3 = fmaf(h3.x, W2[(k0+12)*30 + j], d3);
            d3 = fmaf(h3.y, W2[(k0+13)*30 + j], d3);
            d3 = fmaf(h3.z, W2[(k0+14)*30 + j], d3);
            d3 = fmaf(h3.w, W2[(k0+15)*30 + j], d3);
        }
        float dot = (d0 + d1) + (d2 + d3) + b2[j];
        float sp = fmaxf(dot, 0.f) + log1pf(__expf(-fabsf(dot)));
        const int row = row0 + r;
        if (j < 10)       dmeans[row*NMIX + j]        = sp / 25.0f;
        else if (j < 20)  dvars [row*NMIX + (j-10)]   = fminf(fmaxf(sp, 0.01f), 100.f);
        else              dwts  [row*NMIX + (j-20)]   = sp;
    }
}

// ---------------------------------------------------------------------------
// Kernel 2: parallel inclusive scan over S per (b,k) pair.
// One block of 512 threads per pair; wave shuffle-scan + LDS combine.
// ---------------------------------------------------------------------------
__global__ __launch_bounds__(512) void scan_kernel(
    const float* __restrict__ init_means, float* __restrict__ means)
{
    const int p    = blockIdx.x;          // (b,k) pair, 0..159
    const int s    = threadIdx.x;         // 0..511
    const int lane = s & 63;
    const int wid  = s >> 6;              // 8 waves

    float x = means[s*(BATCH*NMIX) + p];
    #pragma unroll
    for (int d = 1; d < 64; d <<= 1) {
        float t = __shfl_up(x, d, 64);
        if (lane >= d) x += t;
    }
    __shared__ float wsum[8];
    if (lane == 63) wsum[wid] = x;
    __syncthreads();
    float off = init_means[p];
    for (int i = 0; i < wid; i++) off += wsum[i];
    x += off;
    means[s*(BATCH*NMIX) + p] = x;
}

// ---------------------------------------------------------------------------
// Kernel 3: attention weights (unchanged).
// ---------------------------------------------------------------------------
__global__ __launch_bounds__(256) void attn_kernel(
    const float* __restrict__ means, const float* __restrict__ vars,
    const float* __restrict__ wts,   float* __restrict__ attn)
{
    const int row = blockIdx.x;
    const int tid = threadIdx.x;
    float m[NMIX], v[NMIX], w[NMIX];
    #pragma unroll
    for (int k = 0; k < NMIX; k++) {
        m[k] = means[row*NMIX + k];
        v[k] = vars [row*NMIX + k];
        w[k] = wts  [row*NMIX + k];
    }
    const int t0 = tid * 4;
    float o[4];
    #pragma unroll
    for (int i = 0; i < 4; i++) {
        const float t = (float)(t0 + i);
        float sum = 0.f;
        #pragma unroll
        for (int k = 0; k < NMIX; k++) {
            float d = t - m[k];
            sum += w[k] * __expf(-d*d*v[k]);
        }
        o[i] = sum;
    }
    *(float4*)(attn + (size_t)row*NCHAR + t0) = make_float4(o[0],o[1],o[2],o[3]);
}

// ---------------------------------------------------------------------------
// Kernel 4: attended contexts via bf16 MFMA (32x32x16).
// A (attn) staged in LDS, k-contiguous, stride 72 bf16 (conflict-free:
// bank = 4(m+g) mod 32 -> exactly 8 lanes per 4-bank group).
// B (ctx) fragments loaded DIRECTLY from global: lane n=L&31 -> consecutive
// d -> 128B coalesced per half-wave; no transpose anywhere.
// C/D layout (m74/m101): col=lane&31, row=(reg&3)+8*(reg>>2)+4*(lane>>5).
// ---------------------------------------------------------------------------
__global__ __launch_bounds__(256) void ctx_mfma_kernel(
    const float* __restrict__ attn, const float* __restrict__ ctx,
    float* __restrict__ out)
{
    __shared__ __align__(16) unsigned short As[64*72];   // 9216 B
    const int bid  = blockIdx.x;
    const int b    = bid >> 5;
    const int rem  = bid & 31;
    const int s0   = (rem >> 2) * 64;
    const int d0   = (rem & 3)  * 64;
    const int tid  = threadIdx.x;
    const int lane = tid & 63;
    const int w    = tid >> 6;
    const int wr   = (w >> 1) * 32;     // wave row offset in 64-tile
    const int wc   = (w & 1)  * 32;     // wave col offset
    const int m    = lane & 31;
    const int g    = lane >> 5;

    f32x16 acc = {};

    // per-lane column base into ctx: ctx[t][b][d0+wc+m], step t => +BATCH*DCTX
    const float* bcol = ctx + (size_t)b*DCTX + d0 + wc + m;
    const float* arow = attn + (size_t)b*NCHAR;

    for (int kt = 0; kt < NCHAR; kt += 64) {
        __syncthreads();
        #pragma unroll
        for (int q = 0; q < 4; q++) {    // stage A: 64 s x 64 t, fp32->bf16
            int flat = tid + q*256;
            int sl = flat >> 4;
            int t0 = (flat & 15) * 4;
            float4 a4 = *(const float4*)(arow + (size_t)(s0+sl)*(BATCH*NCHAR) + kt + t0);
            unsigned int lo = (unsigned int)f2bf(a4.x) | ((unsigned int)f2bf(a4.y) << 16);
            unsigned int hi = (unsigned int)f2bf(a4.z) | ((unsigned int)f2bf(a4.w) << 16);
            *(uint2*)(As + sl*72 + t0) = make_uint2(lo, hi);
        }
        __syncthreads();
        #pragma unroll
        for (int ks = 0; ks < 64; ks += 16) {
            s16x8 af = *(const s16x8*)(As + (wr + m)*72 + ks + g*8);
            s16x8 bf;
            #pragma unroll
            for (int j = 0; j < 8; j++) {
                int t = kt + ks + g*8 + j;
                bf[j] = (short)f2bf(bcol[(size_t)t*(BATCH*DCTX)]);
            }
            acc = __builtin_amdgcn_mfma_f32_32x32x16_bf16(af, bf, acc, 0, 0, 0);
        }
    }
    #pragma unroll
    for (int r = 0; r < 16; r++) {
        int row = (r & 3) + 8*(r >> 2) + 4*g;
        int s   = s0 + wr + row;
        out[(size_t)s*(BATCH*DCTX) + b*DCTX + d0 + wc + m] = acc[r];
    }
}

// ---------------------------------------------------------------------------
extern "C" void kernel_launch(void* const* d_in, const int* in_sizes, int n_in,
                              void* d_out, int out_size, void* d_ws, size_t ws_size,
                              hipStream_t stream)
{
    const float* X     = (const float*)d_in[0];
    const float* ctx   = (const float*)d_in[1];
    const float* initm = (const float*)d_in[2];
    const float* W1    = (const float*)d_in[3];
    const float* b1    = (const float*)d_in[4];
    const float* W2    = (const float*)d_in[5];
    const float* b2    = (const float*)d_in[6];

    float* out      = (float*)d_out;
    float* out_ctx  = out + OFF_CTXOUT;
    float* out_attn = out + OFF_ATTN;
    float* out_mean = out + OFF_MEANS;
    float* out_var  = out + OFF_VARS;
    float* out_wts  = out + OFF_WTS;

    mlp_kernel<<<M_ROWS/16, 256, 0, stream>>>(X, W1, b1, W2, b2,
                                              out_mean, out_var, out_wts);
    scan_kernel<<<BATCH*NMIX, 512, 0, stream>>>(initm, out_mean);
    attn_kernel<<<M_ROWS, 256, 0, stream>>>(out_mean, out_var, out_wts, out_attn);
    ctx_mfma_kernel<<<16*8*4, 256, 0, stream>>>(out_attn, ctx, out_ctx);
}

// Round 3
// 222.124 us; speedup vs baseline: 1.3014x; 1.0334x over previous
//
#include <hip/hip_runtime.h>
#include <math.h>

#define S_LEN 512
#define BATCH 16
#define DIN   512
#define DF    512
#define NMIX  10
#define NCHAR 1024
#define DCTX  256
#define M_ROWS (S_LEN*BATCH)   // 8192

// d_out layout (tuple flattened in return order)
#define OFF_CTXOUT 0
#define OFF_ATTN   (S_LEN*BATCH*DCTX)
#define OFF_MEANS  (OFF_ATTN + S_LEN*BATCH*NCHAR)
#define OFF_VARS   (OFF_MEANS + S_LEN*BATCH*NMIX)
#define OFF_WTS    (OFF_VARS  + S_LEN*BATCH*NMIX)

// scratch carved out of the attn output region (overwritten by attn_kernel later)
// ushort units: Xh [0, 4194304) | W1h [4194304, 4456448) | Hh [4456448, 8650752)
// then W2T (float) at ushort offset 8650752 (byte 17,301,504; region is 33.5 MB)
#define XH_OFF  0
#define W1H_OFF 4194304
#define HH_OFF  4456448
#define W2T_USHORT_OFF 8650752

#define NX4    1048576    // X float4 count
#define NCVT4  1114112    // X + W1 float4 count
#define CVT_BLOCKS 4352   // NCVT4/256
#define W2T_BLOCKS 61

typedef float    f32x16 __attribute__((ext_vector_type(16)));
typedef _Float16 f16x8  __attribute__((ext_vector_type(8)));

__device__ __forceinline__ unsigned short f2h(float x) {
    union { _Float16 h; unsigned short u; } cv;
    cv.h = (_Float16)x;
    return cv.u;
}

// ---------------------------------------------------------------------------
// Kernel 0: convert X,W1 -> f16 scratch; build W2^T (fp32) scratch.
// ---------------------------------------------------------------------------
__global__ __launch_bounds__(256) void convert_kernel(
    const float* __restrict__ X, const float* __restrict__ W1,
    const float* __restrict__ W2,
    unsigned short* __restrict__ hbase, float* __restrict__ W2T)
{
    const int bid = blockIdx.x;
    if (bid < CVT_BLOCKS) {
        const int i4 = bid*256 + threadIdx.x;
        float4 v = (i4 < NX4) ? ((const float4*)X)[i4]
                              : ((const float4*)W1)[i4 - NX4];
        ushort4 o;
        o.x = f2h(v.x); o.y = f2h(v.y); o.z = f2h(v.z); o.w = f2h(v.w);
        ((ushort4*)hbase)[i4] = o;
    } else {
        const int idx = (bid - CVT_BLOCKS)*256 + threadIdx.x;
        if (idx < 512*30) {
            const int j = idx >> 9, k = idx & 511;
            W2T[idx] = W2[k*30 + j];
        }
    }
}

// ---------------------------------------------------------------------------
// Kernel 1: GEMM1 via f16 MFMA 32x32x16.  h = leaky_relu(X@W1 + b1) -> Hh f16.
// 64x64 tiles, BK=64, grid 128x8=1024 blocks, 4 waves each (2x2 of 32x32).
// LDS stride 72 shorts (144B): fragment b128 reads are conflict-free
// (8 lanes per 4-bank group); transposed B staging writes are 2-way (free).
// ---------------------------------------------------------------------------
__global__ __launch_bounds__(256) void gemm1_kernel(
    const unsigned short* __restrict__ Xh, const unsigned short* __restrict__ W1h,
    const float* __restrict__ b1, unsigned short* __restrict__ Hh)
{
    __shared__ __align__(16) unsigned short As[64*72];
    __shared__ __align__(16) unsigned short Bs[64*72];
    const int row0 = (blockIdx.x >> 3) * 64;
    const int n0   = (blockIdx.x & 7)  * 64;
    const int tid  = threadIdx.x;
    const int lane = tid & 63, w = tid >> 6;
    const int wr = (w >> 1) * 32, wc = (w & 1) * 32;
    const int m  = lane & 31,  g  = lane >> 5;
    const int sa = tid >> 2,   ka = (tid & 3) * 16;   // A staging: row, k-quad
    const int kb = tid & 63,   wb = tid >> 6;         // B staging: k, n-group

    f32x16 acc = {};

    for (int kt = 0; kt < DIN; kt += 64) {
        uint4 av0 = *(const uint4*)(Xh  + (size_t)(row0+sa)*DIN + kt + ka);
        uint4 av1 = *(const uint4*)(Xh  + (size_t)(row0+sa)*DIN + kt + ka + 8);
        uint4 bv0 = *(const uint4*)(W1h + (size_t)(kt+kb)*DF + n0 + wb*16);
        uint4 bv1 = *(const uint4*)(W1h + (size_t)(kt+kb)*DF + n0 + wb*16 + 8);
        __syncthreads();            // previous iter's fragment reads complete
        *(uint4*)(As + sa*72 + ka)     = av0;
        *(uint4*)(As + sa*72 + ka + 8) = av1;
        {
            union { uint4 u; unsigned short s[8]; } p0, p1;
            p0.u = bv0; p1.u = bv1;
            #pragma unroll
            for (int i = 0; i < 8; i++) Bs[(wb*16 + i)*72 + kb]     = p0.s[i];
            #pragma unroll
            for (int i = 0; i < 8; i++) Bs[(wb*16 + 8 + i)*72 + kb] = p1.s[i];
        }
        __syncthreads();
        #pragma unroll
        for (int ks = 0; ks < 64; ks += 16) {
            f16x8 af = *(const f16x8*)(As + (wr+m)*72 + ks + g*8);
            f16x8 bf = *(const f16x8*)(Bs + (wc+m)*72 + ks + g*8);
            acc = __builtin_amdgcn_mfma_f32_32x32x16_f16(af, bf, acc, 0, 0, 0);
        }
    }
    const int ncol = n0 + wc + m;
    const float bb = b1[ncol];
    #pragma unroll
    for (int r = 0; r < 16; r++) {
        const int rowloc = (r & 3) + 8*(r >> 2) + 4*g;
        const int row = row0 + wr + rowloc;
        float v = acc[r] + bb;
        v = v > 0.f ? v : 0.01f * v;
        Hh[(size_t)row*DF + ncol] = f2h(v);
    }
}

// ---------------------------------------------------------------------------
// Kernel 2: GEMM2 (8192x30, K=512) fp32 VALU + softplus + head split.
// 16 rows/block, 512 blocks; thread (row, j) does one dot, 4 partial chains.
// ---------------------------------------------------------------------------
__global__ __launch_bounds__(512) void gemm2_kernel(
    const unsigned short* __restrict__ Hh, const float* __restrict__ W2T,
    const float* __restrict__ b2,
    float* __restrict__ dmeans, float* __restrict__ dvars, float* __restrict__ dwts)
{
    const int t = threadIdx.x;
    if (t >= 480) return;
    const int j   = t % 30;
    const int rr  = t / 30;
    const int row = blockIdx.x * 16 + rr;
    const unsigned short* hrow = Hh  + (size_t)row*DF;
    const float*          wcol = W2T + (size_t)j*DF;

    float c0 = 0.f, c1 = 0.f, c2 = 0.f, c3 = 0.f;
    for (int k0 = 0; k0 < DF; k0 += 32) {
        union { uint4 u; _Float16 h[8]; } hh[4];
        float wv[32];
        #pragma unroll
        for (int q = 0; q < 4; q++) {
            hh[q].u = *(const uint4*)(hrow + k0 + q*8);
            *(float4*)(wv + q*8)     = *(const float4*)(wcol + k0 + q*8);
            *(float4*)(wv + q*8 + 4) = *(const float4*)(wcol + k0 + q*8 + 4);
        }
        #pragma unroll
        for (int i = 0; i < 8; i++) {
            c0 = fmaf((float)hh[0].h[i], wv[i],      c0);
            c1 = fmaf((float)hh[1].h[i], wv[8 + i],  c1);
            c2 = fmaf((float)hh[2].h[i], wv[16 + i], c2);
            c3 = fmaf((float)hh[3].h[i], wv[24 + i], c3);
        }
    }
    float dot = (c0 + c1) + (c2 + c3) + b2[j];
    float sp = fmaxf(dot, 0.f) + log1pf(__expf(-fabsf(dot)));
    if (j < 10)       dmeans[row*NMIX + j]      = sp / 25.0f;
    else if (j < 20)  dvars [row*NMIX + (j-10)] = fminf(fmaxf(sp, 0.01f), 100.f);
    else              dwts  [row*NMIX + (j-20)] = sp;
}

// ---------------------------------------------------------------------------
// Kernel 3: parallel inclusive scan over S per (b,k) pair.
// ---------------------------------------------------------------------------
__global__ __launch_bounds__(512) void scan_kernel(
    const float* __restrict__ init_means, float* __restrict__ means)
{
    const int p    = blockIdx.x;
    const int s    = threadIdx.x;
    const int lane = s & 63;
    const int wid  = s >> 6;

    float x = means[s*(BATCH*NMIX) + p];
    #pragma unroll
    for (int d = 1; d < 64; d <<= 1) {
        float tv = __shfl_up(x, d, 64);
        if (lane >= d) x += tv;
    }
    __shared__ float wsum[8];
    if (lane == 63) wsum[wid] = x;
    __syncthreads();
    float off = init_means[p];
    for (int i = 0; i < wid; i++) off += wsum[i];
    x += off;
    means[s*(BATCH*NMIX) + p] = x;
}

// ---------------------------------------------------------------------------
// Kernel 4: attention weights.
// ---------------------------------------------------------------------------
__global__ __launch_bounds__(256) void attn_kernel(
    const float* __restrict__ means, const float* __restrict__ vars,
    const float* __restrict__ wts,   float* __restrict__ attn)
{
    const int row = blockIdx.x;
    const int tid = threadIdx.x;
    float m[NMIX], v[NMIX], w[NMIX];
    #pragma unroll
    for (int k = 0; k < NMIX; k++) {
        m[k] = means[row*NMIX + k];
        v[k] = vars [row*NMIX + k];
        w[k] = wts  [row*NMIX + k];
    }
    const int t0 = tid * 4;
    float o[4];
    #pragma unroll
    for (int i = 0; i < 4; i++) {
        const float t = (float)(t0 + i);
        float sum = 0.f;
        #pragma unroll
        for (int k = 0; k < NMIX; k++) {
            float d = t - m[k];
            sum += w[k] * __expf(-d*d*v[k]);
        }
        o[i] = sum;
    }
    *(float4*)(attn + (size_t)row*NCHAR + t0) = make_float4(o[0],o[1],o[2],o[3]);
}

// ---------------------------------------------------------------------------
// Kernel 5: attended contexts via f16 MFMA, BOTH operands LDS-staged.
// ---------------------------------------------------------------------------
__global__ __launch_bounds__(256) void ctx_mfma_kernel(
    const float* __restrict__ attn, const float* __restrict__ ctx,
    float* __restrict__ out)
{
    __shared__ __align__(16) unsigned short As[64*72];
    __shared__ __align__(16) unsigned short Bs[64*72];
    const int bid  = blockIdx.x;
    const int b    = bid >> 5;
    const int rem  = bid & 31;
    const int s0   = (rem >> 2) * 64;
    const int d0   = (rem & 3)  * 64;
    const int tid  = threadIdx.x;
    const int lane = tid & 63, w = tid >> 6;
    const int wr = (w >> 1) * 32, wc = (w & 1) * 32;
    const int m  = lane & 31,  g  = lane >> 5;
    const int tb = tid & 63,   wb = tid >> 6;    // B staging: t, d-group

    f32x16 acc = {};
    const float* arow = attn + (size_t)b*NCHAR;
    const float* brow = ctx  + (size_t)b*DCTX + d0 + wb*16;

    for (int kt = 0; kt < NCHAR; kt += 64) {
        // A tile: 64 s x 64 t, fp32 -> f16
        float4 a4[4];
        #pragma unroll
        for (int q = 0; q < 4; q++) {
            int flat = tid + q*256;
            int sl = flat >> 4;
            int t0 = (flat & 15) * 4;
            a4[q] = *(const float4*)(arow + (size_t)(s0+sl)*(BATCH*NCHAR) + kt + t0);
        }
        // B tile: 64 t x 64 d, fp32 -> f16, transposed to Bs[d][t]
        float4 b4[4];
        #pragma unroll
        for (int q = 0; q < 4; q++)
            b4[q] = *(const float4*)(brow + (size_t)(kt+tb)*(BATCH*DCTX) + q*4);
        __syncthreads();
        #pragma unroll
        for (int q = 0; q < 4; q++) {
            int flat = tid + q*256;
            int sl = flat >> 4;
            int t0 = (flat & 15) * 4;
            unsigned int lo = (unsigned int)f2h(a4[q].x) | ((unsigned int)f2h(a4[q].y) << 16);
            unsigned int hi = (unsigned int)f2h(a4[q].z) | ((unsigned int)f2h(a4[q].w) << 16);
            *(uint2*)(As + sl*72 + t0) = make_uint2(lo, hi);
        }
        #pragma unroll
        for (int q = 0; q < 4; q++) {
            Bs[(wb*16 + q*4 + 0)*72 + tb] = f2h(b4[q].x);
            Bs[(wb*16 + q*4 + 1)*72 + tb] = f2h(b4[q].y);
            Bs[(wb*16 + q*4 + 2)*72 + tb] = f2h(b4[q].z);
            Bs[(wb*16 + q*4 + 3)*72 + tb] = f2h(b4[q].w);
        }
        __syncthreads();
        #pragma unroll
        for (int ks = 0; ks < 64; ks += 16) {
            f16x8 af = *(const f16x8*)(As + (wr+m)*72 + ks + g*8);
            f16x8 bf = *(const f16x8*)(Bs + (wc+m)*72 + ks + g*8);
            acc = __builtin_amdgcn_mfma_f32_32x32x16_f16(af, bf, acc, 0, 0, 0);
        }
    }
    #pragma unroll
    for (int r = 0; r < 16; r++) {
        int rowloc = (r & 3) + 8*(r >> 2) + 4*g;
        int s = s0 + wr + rowloc;
        out[(size_t)s*(BATCH*DCTX) + b*DCTX + d0 + wc + m] = acc[r];
    }
}

// ---------------------------------------------------------------------------
extern "C" void kernel_launch(void* const* d_in, const int* in_sizes, int n_in,
                              void* d_out, int out_size, void* d_ws, size_t ws_size,
                              hipStream_t stream)
{
    const float* X     = (const float*)d_in[0];
    const float* ctx   = (const float*)d_in[1];
    const float* initm = (const float*)d_in[2];
    const float* W1    = (const float*)d_in[3];
    const float* b1    = (const float*)d_in[4];
    const float* W2    = (const float*)d_in[5];
    const float* b2    = (const float*)d_in[6];

    float* out      = (float*)d_out;
    float* out_ctx  = out + OFF_CTXOUT;
    float* out_attn = out + OFF_ATTN;
    float* out_mean = out + OFF_MEANS;
    float* out_var  = out + OFF_VARS;
    float* out_wts  = out + OFF_WTS;

    unsigned short* hbase = (unsigned short*)out_attn;    // scratch inside attn region
    unsigned short* Xh    = hbase + XH_OFF;
    unsigned short* W1h   = hbase + W1H_OFF;
    unsigned short* Hh    = hbase + HH_OFF;
    float*          W2T   = (float*)(hbase + W2T_USHORT_OFF);

    convert_kernel<<<CVT_BLOCKS + W2T_BLOCKS, 256, 0, stream>>>(X, W1, W2, hbase, W2T);
    gemm1_kernel<<<(M_ROWS/64)*(DF/64), 256, 0, stream>>>(Xh, W1h, b1, Hh);
    gemm2_kernel<<<M_ROWS/16, 512, 0, stream>>>(Hh, W2T, b2, out_mean, out_var, out_wts);
    scan_kernel<<<BATCH*NMIX, 512, 0, stream>>>(initm, out_mean);
    attn_kernel<<<M_ROWS, 256, 0, stream>>>(out_mean, out_var, out_wts, out_attn);
    ctx_mfma_kernel<<<16*8*4, 256, 0, stream>>>(out_attn, ctx, out_ctx);
}

// Round 4
// 179.187 us; speedup vs baseline: 1.6132x; 1.2396x over previous
//
#include <hip/hip_runtime.h>
#include <math.h>

#define S_LEN 512
#define BATCH 16
#define DIN   512
#define DF    512
#define NMIX  10
#define NCHAR 1024
#define DCTX  256
#define M_ROWS (S_LEN*BATCH)   // 8192

// d_out layout (tuple flattened in return order)
#define OFF_CTXOUT 0
#define OFF_ATTN   (S_LEN*BATCH*DCTX)
#define OFF_MEANS  (OFF_ATTN + S_LEN*BATCH*NCHAR)
#define OFF_VARS   (OFF_MEANS + S_LEN*BATCH*NMIX)
#define OFF_WTS    (OFF_VARS  + S_LEN*BATCH*NMIX)

// scratch carved out of the attn output region (overwritten by attn_kernel later)
// ushort units: Xh [0, 4194304) | W1h [4194304, 4456448) | Hh [4456448, 8650752)
// then W2T (float, 32x512 zero-padded) at ushort offset 8650752
#define XH_OFF  0
#define W1H_OFF 4194304
#define HH_OFF  4456448
#define W2T_USHORT_OFF 8650752

#define NX4    1048576    // X float4 count
#define NCVT4  1114112    // X + W1 float4 count
#define CVT_BLOCKS 4352   // NCVT4/256
#define W2T_BLOCKS 64     // 512*32/256

typedef float    f32x16 __attribute__((ext_vector_type(16)));
typedef _Float16 f16x8  __attribute__((ext_vector_type(8)));

__device__ __forceinline__ unsigned short f2h(float x) {
    union { _Float16 h; unsigned short u; } cv;
    cv.h = (_Float16)x;
    return cv.u;
}

// ---------------------------------------------------------------------------
// Kernel 0: convert X,W1 -> f16 scratch; build W2^T (fp32, padded 32 rows).
// ---------------------------------------------------------------------------
__global__ __launch_bounds__(256) void convert_kernel(
    const float* __restrict__ X, const float* __restrict__ W1,
    const float* __restrict__ W2,
    unsigned short* __restrict__ hbase, float* __restrict__ W2T)
{
    const int bid = blockIdx.x;
    if (bid < CVT_BLOCKS) {
        const int i4 = bid*256 + threadIdx.x;
        float4 v = (i4 < NX4) ? ((const float4*)X)[i4]
                              : ((const float4*)W1)[i4 - NX4];
        ushort4 o;
        o.x = f2h(v.x); o.y = f2h(v.y); o.z = f2h(v.z); o.w = f2h(v.w);
        ((ushort4*)hbase)[i4] = o;
    } else {
        const int idx = (bid - CVT_BLOCKS)*256 + threadIdx.x;
        if (idx < 512*32) {
            const int j = idx >> 9, k = idx & 511;
            W2T[idx] = (j < 30) ? W2[k*30 + j] : 0.f;
        }
    }
}

// ---------------------------------------------------------------------------
// Kernel 1: GEMM1 via f16 MFMA 32x32x16.  h = leaky_relu(X@W1 + b1) -> Hh f16.
// ---------------------------------------------------------------------------
__global__ __launch_bounds__(256) void gemm1_kernel(
    const unsigned short* __restrict__ Xh, const unsigned short* __restrict__ W1h,
    const float* __restrict__ b1, unsigned short* __restrict__ Hh)
{
    __shared__ __align__(16) unsigned short As[64*72];
    __shared__ __align__(16) unsigned short Bs[64*72];
    const int row0 = (blockIdx.x >> 3) * 64;
    const int n0   = (blockIdx.x & 7)  * 64;
    const int tid  = threadIdx.x;
    const int lane = tid & 63, w = tid >> 6;
    const int wr = (w >> 1) * 32, wc = (w & 1) * 32;
    const int m  = lane & 31,  g  = lane >> 5;
    const int sa = tid >> 2,   ka = (tid & 3) * 16;   // A staging: row, k-quad
    const int kb = tid & 63,   wb = tid >> 6;         // B staging: k, n-group

    f32x16 acc = {};

    for (int kt = 0; kt < DIN; kt += 64) {
        uint4 av0 = *(const uint4*)(Xh  + (size_t)(row0+sa)*DIN + kt + ka);
        uint4 av1 = *(const uint4*)(Xh  + (size_t)(row0+sa)*DIN + kt + ka + 8);
        uint4 bv0 = *(const uint4*)(W1h + (size_t)(kt+kb)*DF + n0 + wb*16);
        uint4 bv1 = *(const uint4*)(W1h + (size_t)(kt+kb)*DF + n0 + wb*16 + 8);
        __syncthreads();
        *(uint4*)(As + sa*72 + ka)     = av0;
        *(uint4*)(As + sa*72 + ka + 8) = av1;
        {
            union { uint4 u; unsigned short s[8]; } p0, p1;
            p0.u = bv0; p1.u = bv1;
            #pragma unroll
            for (int i = 0; i < 8; i++) Bs[(wb*16 + i)*72 + kb]     = p0.s[i];
            #pragma unroll
            for (int i = 0; i < 8; i++) Bs[(wb*16 + 8 + i)*72 + kb] = p1.s[i];
        }
        __syncthreads();
        #pragma unroll
        for (int ks = 0; ks < 64; ks += 16) {
            f16x8 af = *(const f16x8*)(As + (wr+m)*72 + ks + g*8);
            f16x8 bf = *(const f16x8*)(Bs + (wc+m)*72 + ks + g*8);
            acc = __builtin_amdgcn_mfma_f32_32x32x16_f16(af, bf, acc, 0, 0, 0);
        }
    }
    const int ncol = n0 + wc + m;
    const float bb = b1[ncol];
    #pragma unroll
    for (int r = 0; r < 16; r++) {
        const int rowloc = (r & 3) + 8*(r >> 2) + 4*g;
        const int row = row0 + wr + rowloc;
        float v = acc[r] + bb;
        v = v > 0.f ? v : 0.01f * v;
        Hh[(size_t)row*DF + ncol] = f2h(v);
    }
}

// ---------------------------------------------------------------------------
// Kernel 2: GEMM2 (8192x30, K=512), LDS-staged H, broadcast W2T reads.
// 256 blocks x 32 rows.  Thread (r=tid&31, j0=tid>>5) -> j0, j0+8, +16, +24.
// One LDS b128 h-read feeds 4 output chains; W2T same-address across lanes.
// ---------------------------------------------------------------------------
__global__ __launch_bounds__(256) void gemm2_kernel(
    const unsigned short* __restrict__ Hh, const float* __restrict__ W2T,
    const float* __restrict__ b2,
    float* __restrict__ dmeans, float* __restrict__ dvars, float* __restrict__ dwts)
{
    __shared__ __align__(16) unsigned short Hs[32*520];
    const int tid = threadIdx.x;
    const int r0  = blockIdx.x * 32;
    {
        const uint4* src = (const uint4*)(Hh + (size_t)r0*DF);
        #pragma unroll
        for (int i = 0; i < 8; i++) {
            int u   = tid + i*256;
            int row = u >> 6;             // 64 uint4 per row
            int col = (u & 63) * 8;
            *(uint4*)(Hs + row*520 + col) = src[u];
        }
    }
    __syncthreads();

    const int r  = tid & 31;
    const int j0 = tid >> 5;       // 0..7
    const unsigned short* hrow = Hs + r*520;
    float acc[4] = {0.f, 0.f, 0.f, 0.f};

    for (int k0 = 0; k0 < DF; k0 += 8) {
        union { uint4 u; _Float16 h[8]; } hv;
        hv.u = *(const uint4*)(hrow + k0);
        float wv[4][8];
        #pragma unroll
        for (int q = 0; q < 4; q++) {
            *(float4*)(wv[q])     = *(const float4*)(W2T + (size_t)(j0 + q*8)*DF + k0);
            *(float4*)(wv[q] + 4) = *(const float4*)(W2T + (size_t)(j0 + q*8)*DF + k0 + 4);
        }
        #pragma unroll
        for (int i = 0; i < 8; i++) {
            float hf = (float)hv.h[i];
            acc[0] = fmaf(hf, wv[0][i], acc[0]);
            acc[1] = fmaf(hf, wv[1][i], acc[1]);
            acc[2] = fmaf(hf, wv[2][i], acc[2]);
            acc[3] = fmaf(hf, wv[3][i], acc[3]);
        }
    }
    const int row = r0 + r;
    #pragma unroll
    for (int q = 0; q < 4; q++) {
        const int j = j0 + q*8;
        if (j >= 30) continue;            // padded cols
        float dot = acc[q] + b2[j];
        float sp  = fmaxf(dot, 0.f) + log1pf(__expf(-fabsf(dot)));
        if (j < 10)       dmeans[row*NMIX + j]      = sp / 25.0f;
        else if (j < 20)  dvars [row*NMIX + (j-10)] = fminf(fmaxf(sp, 0.01f), 100.f);
        else              dwts  [row*NMIX + (j-20)] = sp;
    }
}

// ---------------------------------------------------------------------------
// Kernel 3: parallel inclusive scan over S per (b,k) pair.
// ---------------------------------------------------------------------------
__global__ __launch_bounds__(512) void scan_kernel(
    const float* __restrict__ init_means, float* __restrict__ means)
{
    const int p    = blockIdx.x;
    const int s    = threadIdx.x;
    const int lane = s & 63;
    const int wid  = s >> 6;

    float x = means[s*(BATCH*NMIX) + p];
    #pragma unroll
    for (int d = 1; d < 64; d <<= 1) {
        float tv = __shfl_up(x, d, 64);
        if (lane >= d) x += tv;
    }
    __shared__ float wsum[8];
    if (lane == 63) wsum[wid] = x;
    __syncthreads();
    float off = init_means[p];
    for (int i = 0; i < wid; i++) off += wsum[i];
    x += off;
    means[s*(BATCH*NMIX) + p] = x;
}

// ---------------------------------------------------------------------------
// Kernel 4: attention weights.
// ---------------------------------------------------------------------------
__global__ __launch_bounds__(256) void attn_kernel(
    const float* __restrict__ means, const float* __restrict__ vars,
    const float* __restrict__ wts,   float* __restrict__ attn)
{
    const int row = blockIdx.x;
    const int tid = threadIdx.x;
    float m[NMIX], v[NMIX], w[NMIX];
    #pragma unroll
    for (int k = 0; k < NMIX; k++) {
        m[k] = means[row*NMIX + k];
        v[k] = vars [row*NMIX + k];
        w[k] = wts  [row*NMIX + k];
    }
    const int t0 = tid * 4;
    float o[4];
    #pragma unroll
    for (int i = 0; i < 4; i++) {
        const float t = (float)(t0 + i);
        float sum = 0.f;
        #pragma unroll
        for (int k = 0; k < NMIX; k++) {
            float d = t - m[k];
            sum += w[k] * __expf(-d*d*v[k]);
        }
        o[i] = sum;
    }
    *(float4*)(attn + (size_t)row*NCHAR + t0) = make_float4(o[0],o[1],o[2],o[3]);
}

// ---------------------------------------------------------------------------
// Kernel 5: attended contexts via f16 MFMA, BOTH operands LDS-staged.
// ---------------------------------------------------------------------------
__global__ __launch_bounds__(256) void ctx_mfma_kernel(
    const float* __restrict__ attn, const float* __restrict__ ctx,
    float* __restrict__ out)
{
    __shared__ __align__(16) unsigned short As[64*72];
    __shared__ __align__(16) unsigned short Bs[64*72];
    const int bid  = blockIdx.x;
    const int b    = bid >> 5;
    const int rem  = bid & 31;
    const int s0   = (rem >> 2) * 64;
    const int d0   = (rem & 3)  * 64;
    const int tid  = threadIdx.x;
    const int lane = tid & 63, w = tid >> 6;
    const int wr = (w >> 1) * 32, wc = (w & 1) * 32;
    const int m  = lane & 31,  g  = lane >> 5;
    const int tb = tid & 63,   wb = tid >> 6;    // B staging: t, d-group

    f32x16 acc = {};
    const float* arow = attn + (size_t)b*NCHAR;
    const float* brow = ctx  + (size_t)b*DCTX + d0 + wb*16;

    for (int kt = 0; kt < NCHAR; kt += 64) {
        float4 a4[4];
        #pragma unroll
        for (int q = 0; q < 4; q++) {
            int flat = tid + q*256;
            int sl = flat >> 4;
            int t0 = (flat & 15) * 4;
            a4[q] = *(const float4*)(arow + (size_t)(s0+sl)*(BATCH*NCHAR) + kt + t0);
        }
        float4 b4[4];
        #pragma unroll
        for (int q = 0; q < 4; q++)
            b4[q] = *(const float4*)(brow + (size_t)(kt+tb)*(BATCH*DCTX) + q*4);
        __syncthreads();
        #pragma unroll
        for (int q = 0; q < 4; q++) {
            int flat = tid + q*256;
            int sl = flat >> 4;
            int t0 = (flat & 15) * 4;
            unsigned int lo = (unsigned int)f2h(a4[q].x) | ((unsigned int)f2h(a4[q].y) << 16);
            unsigned int hi = (unsigned int)f2h(a4[q].z) | ((unsigned int)f2h(a4[q].w) << 16);
            *(uint2*)(As + sl*72 + t0) = make_uint2(lo, hi);
        }
        #pragma unroll
        for (int q = 0; q < 4; q++) {
            Bs[(wb*16 + q*4 + 0)*72 + tb] = f2h(b4[q].x);
            Bs[(wb*16 + q*4 + 1)*72 + tb] = f2h(b4[q].y);
            Bs[(wb*16 + q*4 + 2)*72 + tb] = f2h(b4[q].z);
            Bs[(wb*16 + q*4 + 3)*72 + tb] = f2h(b4[q].w);
        }
        __syncthreads();
        #pragma unroll
        for (int ks = 0; ks < 64; ks += 16) {
            f16x8 af = *(const f16x8*)(As + (wr+m)*72 + ks + g*8);
            f16x8 bf = *(const f16x8*)(Bs + (wc+m)*72 + ks + g*8);
            acc = __builtin_amdgcn_mfma_f32_32x32x16_f16(af, bf, acc, 0, 0, 0);
        }
    }
    #pragma unroll
    for (int r = 0; r < 16; r++) {
        int rowloc = (r & 3) + 8*(r >> 2) + 4*g;
        int s = s0 + wr + rowloc;
        out[(size_t)s*(BATCH*DCTX) + b*DCTX + d0 + wc + m] = acc[r];
    }
}

// ---------------------------------------------------------------------------
extern "C" void kernel_launch(void* const* d_in, const int* in_sizes, int n_in,
                              void* d_out, int out_size, void* d_ws, size_t ws_size,
                              hipStream_t stream)
{
    const float* X     = (const float*)d_in[0];
    const float* ctx   = (const float*)d_in[1];
    const float* initm = (const float*)d_in[2];
    const float* W1    = (const float*)d_in[3];
    const float* b1    = (const float*)d_in[4];
    const float* W2    = (const float*)d_in[5];
    const float* b2    = (const float*)d_in[6];

    float* out      = (float*)d_out;
    float* out_ctx  = out + OFF_CTXOUT;
    float* out_attn = out + OFF_ATTN;
    float* out_mean = out + OFF_MEANS;
    float* out_var  = out + OFF_VARS;
    float* out_wts  = out + OFF_WTS;

    unsigned short* hbase = (unsigned short*)out_attn;    // scratch inside attn region
    unsigned short* Xh    = hbase + XH_OFF;
    unsigned short* W1h   = hbase + W1H_OFF;
    unsigned short* Hh    = hbase + HH_OFF;
    float*          W2T   = (float*)(hbase + W2T_USHORT_OFF);

    convert_kernel<<<CVT_BLOCKS + W2T_BLOCKS, 256, 0, stream>>>(X, W1, W2, hbase, W2T);
    gemm1_kernel<<<(M_ROWS/64)*(DF/64), 256, 0, stream>>>(Xh, W1h, b1, Hh);
    gemm2_kernel<<<M_ROWS/32, 256, 0, stream>>>(Hh, W2T, b2, out_mean, out_var, out_wts);
    scan_kernel<<<BATCH*NMIX, 512, 0, stream>>>(initm, out_mean);
    attn_kernel<<<M_ROWS, 256, 0, stream>>>(out_mean, out_var, out_wts, out_attn);
    ctx_mfma_kernel<<<16*8*4, 256, 0, stream>>>(out_attn, ctx, out_ctx);
}